// Round 5
// baseline (806.354 us; speedup 1.0000x reference)
//
#include <hip/hip_runtime.h>
#include <cstdint>
#include <cstddef>

#define NN 50000
#define EE 800000
#define INF 512
#define HH  256
#define CC  10
#define NB  196            // ceil(NN/256) for scan
#define NTB 782            // ceil(NN/64)  tail blocks
#define GPB 196            // spmm blocks per column group

using bfrag = __attribute__((ext_vector_type(8))) __bf16;
using f32x4 = __attribute__((ext_vector_type(4))) float;

__device__ inline unsigned short f2bf(float x) {
    unsigned u = __builtin_bit_cast(unsigned, x);
    unsigned r = u + 0x7FFFu + ((u >> 16) & 1u);
    return (unsigned short)(r >> 16);
}
__device__ inline float bf2f(unsigned short h) {
    return __builtin_bit_cast(float, (unsigned)h << 16);
}

// ---------------------------------------------------------------- weight casts
// W [K][256] fp32 -> Wt [256][K] bf16
template<int K>
__global__ void k_cast_wt(const float* __restrict__ W, ushort* __restrict__ Wt) {
    int idx = blockIdx.x * blockDim.x + threadIdx.x;
    if (idx >= K * HH) return;
    int n = idx / K, k = idx % K;
    Wt[idx] = f2bf(W[(size_t)k * HH + n]);
}

// Wt1[16][256]: rows 0-9 = Wfc cols, rows 10/11 = Wd[256:512] cols, 12-15 = 0
__global__ void k_cast_wtail(const float* __restrict__ Wfc, const float* __restrict__ Wd,
                             ushort* __restrict__ Wt1) {
    int idx = blockIdx.x * blockDim.x + threadIdx.x;
    if (idx >= 16 * HH) return;
    int n = idx >> 8, k = idx & 255;
    float v = 0.f;
    if (n < 10)       v = Wfc[(size_t)k * 10 + n];
    else if (n < 12)  v = Wd[(size_t)(HH + k) * 2 + (n - 10)];
    Wt1[idx] = f2bf(v);
}

// Wt2[16][256]: rows 0/1 = Wd[0:256] cols, rest 0
__global__ void k_cast_wtail2(const float* __restrict__ Wd, ushort* __restrict__ Wt2) {
    int idx = blockIdx.x * blockDim.x + threadIdx.x;
    if (idx >= 16 * HH) return;
    int n = idx >> 8, k = idx & 255;
    float v = (n < 2) ? Wd[(size_t)k * 2 + n] : 0.f;
    Wt2[idx] = f2bf(v);
}

// ---------------------------------------------------------------- degrees
__global__ void k_degrees(const int* __restrict__ src, const int* __restrict__ dst,
                          int* __restrict__ cnt_out, int* __restrict__ cnt_in) {
    int e = blockIdx.x * blockDim.x + threadIdx.x;
    if (e >= EE) return;
    atomicAdd(&cnt_out[src[e]], 1);
    atomicAdd(&cnt_in[dst[e]], 1);
}

// ------------------------------------------------- 3-phase exclusive scan
__global__ void k_scan_blk(const int* __restrict__ counts, int* __restrict__ off,
                           int* __restrict__ btot) {
    __shared__ int wsum[4];
    int tid = threadIdx.x, lane = tid & 63, wid = tid >> 6;
    int i = blockIdx.x * 256 + tid;
    int v = (i < NN) ? counts[i] : 0;
    int s = v;
    #pragma unroll
    for (int o = 1; o < 64; o <<= 1) {
        int t = __shfl_up(s, o, 64);
        if (lane >= o) s += t;
    }
    if (lane == 63) wsum[wid] = s;
    __syncthreads();
    if (tid == 0) {
        int a = 0;
        #pragma unroll
        for (int w2 = 0; w2 < 4; ++w2) { int t = wsum[w2]; wsum[w2] = a; a += t; }
        btot[blockIdx.x] = a;
    }
    __syncthreads();
    if (i < NN) off[i] = wsum[wid] + s - v;
}

__global__ void k_scan_tops(const int* __restrict__ btot, int* __restrict__ bbase,
                            int* __restrict__ off) {
    __shared__ int wsum[4];
    int tid = threadIdx.x, lane = tid & 63, wid = tid >> 6;
    int v = (tid < NB) ? btot[tid] : 0;
    int s = v;
    #pragma unroll
    for (int o = 1; o < 64; o <<= 1) {
        int t = __shfl_up(s, o, 64);
        if (lane >= o) s += t;
    }
    if (lane == 63) wsum[wid] = s;
    __syncthreads();
    if (tid == 0) {
        int a = 0;
        #pragma unroll
        for (int w2 = 0; w2 < 4; ++w2) { int t = wsum[w2]; wsum[w2] = a; a += t; }
        off[NN] = a;
    }
    __syncthreads();
    if (tid < NB) bbase[tid] = wsum[wid] + s - v;
}

// fixup + norms + cur copy
__global__ void k_scan_fin(int* __restrict__ off, const int* __restrict__ bbase,
                           int* __restrict__ cur, const int* __restrict__ cnt_out,
                           const int* __restrict__ cnt_in, float* __restrict__ norm_src,
                           float* __restrict__ norm_dst) {
    int i = blockIdx.x * blockDim.x + threadIdx.x;
    if (i >= NN) return;
    int o = off[i] + bbase[i >> 8];
    off[i] = o;
    cur[i] = o;
    norm_src[i] = 1.0f / sqrtf(fmaxf((float)cnt_out[i], 1.0f));
    norm_dst[i] = 1.0f / sqrtf(fmaxf((float)cnt_in[i], 1.0f));
}

__global__ void k_fill(const int* __restrict__ src, const int* __restrict__ dst,
                       int* __restrict__ cur, int* __restrict__ csr_src) {
    int e = blockIdx.x * blockDim.x + threadIdx.x;
    if (e >= EE) return;
    int p = atomicAdd(&cur[dst[e]], 1);
    csr_src[p] = src[e];
}

// ---------------------------------------------------------------- MFMA GEMM
// Y[M][256] = (A @ W) * ns[row], bf16 MFMA, 128x128 tile, 4 waves.
template<int K, bool F32A>
__global__ __launch_bounds__(256) void k_gemm(
        const void* __restrict__ Ap, const ushort* __restrict__ Bt,
        const float* __restrict__ norm_src, ushort* __restrict__ Y) {
    __shared__ ushort As[128 * 64];
    __shared__ ushort Bs[128 * 64];
    const int m0 = blockIdx.x * 128;
    const int n0 = blockIdx.y * 128;
    const int t = threadIdx.x;
    const int wid = t >> 6, lane = t & 63;
    const int wr = (wid >> 1) * 64, wc = (wid & 1) * 64;
    const int l15 = lane & 15, lg = lane >> 4;

    f32x4 acc[4][4];
    for (int m = 0; m < 4; ++m)
        for (int n = 0; n < 4; ++n)
            acc[m][n] = {0.f, 0.f, 0.f, 0.f};

    const int srow = t >> 3;
    const int schunk = t & 7;

    for (int k0 = 0; k0 < K; k0 += 64) {
        #pragma unroll
        for (int i = 0; i < 4; ++i) {
            int row = srow + i * 32;
            int sw = ((schunk ^ (row & 7)) * 8);
            int m = m0 + row; if (m >= NN) m = NN - 1;
            uint4 va;
            if constexpr (F32A) {
                const float* ap = (const float*)Ap + (size_t)m * K + k0 + schunk * 8;
                float4 f0 = *reinterpret_cast<const float4*>(ap);
                float4 f1 = *reinterpret_cast<const float4*>(ap + 4);
                va.x = (unsigned)f2bf(f0.x) | ((unsigned)f2bf(f0.y) << 16);
                va.y = (unsigned)f2bf(f0.z) | ((unsigned)f2bf(f0.w) << 16);
                va.z = (unsigned)f2bf(f1.x) | ((unsigned)f2bf(f1.y) << 16);
                va.w = (unsigned)f2bf(f1.z) | ((unsigned)f2bf(f1.w) << 16);
            } else {
                va = *reinterpret_cast<const uint4*>((const ushort*)Ap + (size_t)m * K + k0 + schunk * 8);
            }
            *reinterpret_cast<uint4*>(&As[row * 64 + sw]) = va;
            int nb = n0 + row;
            uint4 vb = *reinterpret_cast<const uint4*>(&Bt[(size_t)nb * K + k0 + schunk * 8]);
            *reinterpret_cast<uint4*>(&Bs[row * 64 + sw]) = vb;
        }
        __syncthreads();
        #pragma unroll
        for (int kk = 0; kk < 64; kk += 32) {
            const int kc = kk >> 3;
            bfrag af[4], bg[4];
            #pragma unroll
            for (int m = 0; m < 4; ++m) {
                int row = wr + m * 16 + l15;
                af[m] = *reinterpret_cast<const bfrag*>(&As[row * 64 + (((lg + kc) ^ (row & 7)) * 8)]);
            }
            #pragma unroll
            for (int n = 0; n < 4; ++n) {
                int row = wc + n * 16 + l15;
                bg[n] = *reinterpret_cast<const bfrag*>(&Bs[row * 64 + (((lg + kc) ^ (row & 7)) * 8)]);
            }
            #pragma unroll
            for (int m = 0; m < 4; ++m)
                #pragma unroll
                for (int n = 0; n < 4; ++n)
                    acc[m][n] = __builtin_amdgcn_mfma_f32_16x16x32_bf16(af[m], bg[n], acc[m][n], 0, 0, 0);
        }
        __syncthreads();
    }
    #pragma unroll
    for (int m = 0; m < 4; ++m) {
        #pragma unroll
        for (int r = 0; r < 4; ++r) {
            int row = m0 + wr + m * 16 + lg * 4 + r;
            if (row >= NN) continue;
            float ns = norm_src[row];
            #pragma unroll
            for (int n = 0; n < 4; ++n) {
                int col = n0 + wc + n * 16 + l15;
                Y[(size_t)row * 256 + col] = f2bf(acc[m][n][r] * ns);
            }
        }
    }
}

// ------------------------------------------------- SpMM, column-split + XCD-pinned
// group = blockIdx.x & 7 -> 32-col slice (3.2 MB of y) stays in one XCD's L2.
// 4 lanes per node (one 16B chunk each), 16 nodes per wave, no shuffles.
__device__ inline void add8(float* a, uint4 v) {
    a[0] += __builtin_bit_cast(float, v.x << 16);
    a[1] += __builtin_bit_cast(float, v.x & 0xffff0000u);
    a[2] += __builtin_bit_cast(float, v.y << 16);
    a[3] += __builtin_bit_cast(float, v.y & 0xffff0000u);
    a[4] += __builtin_bit_cast(float, v.z << 16);
    a[5] += __builtin_bit_cast(float, v.z & 0xffff0000u);
    a[6] += __builtin_bit_cast(float, v.w << 16);
    a[7] += __builtin_bit_cast(float, v.w & 0xffff0000u);
}

__global__ __launch_bounds__(256) void k_spmm2(
        const ushort* __restrict__ y, const int* __restrict__ off,
        const int* __restrict__ csr_src, const float* __restrict__ norm_dst,
        const float* __restrict__ bias, ushort* __restrict__ h_out) {
    const int grp = blockIdx.x & 7;
    const int blk = blockIdx.x >> 3;
    const int lane = threadIdx.x & 63;
    const int wid = threadIdx.x >> 6;
    const int slot = lane >> 2;
    const int colb = grp * 32 + (lane & 3) * 8;

    float bia[8];
    #pragma unroll
    for (int j = 0; j < 8; ++j) bia[j] = bias[colb + j];

    const int stride = GPB * 4 * 16;     // nodes covered per sweep by one group
    for (int nb = (blk * 4 + wid) * 16; nb < NN; nb += stride) {
        int n = nb + slot;
        bool nv = n < NN;
        int s0 = nv ? off[n] : 0;
        int s1 = nv ? off[n + 1] : 0;
        float a[8] = {0.f, 0.f, 0.f, 0.f, 0.f, 0.f, 0.f, 0.f};
        for (int e = s0; ; ++e) {
            bool v = e < s1;
            if (!__any(v)) break;
            if (v) {
                int s = csr_src[e];
                uint4 vv = *reinterpret_cast<const uint4*>(&y[(size_t)s * 256 + colb]);
                add8(a, vv);
            }
        }
        if (nv) {
            float nd = norm_dst[n];
            ushort r[8];
            #pragma unroll
            for (int j = 0; j < 8; ++j) r[j] = f2bf(fmaxf(a[j] * nd + bia[j], 0.f));
            uint4 pk;
            pk.x = (unsigned)r[0] | ((unsigned)r[1] << 16);
            pk.y = (unsigned)r[2] | ((unsigned)r[3] << 16);
            pk.z = (unsigned)r[4] | ((unsigned)r[5] << 16);
            pk.w = (unsigned)r[6] | ((unsigned)r[7] << 16);
            *reinterpret_cast<uint4*>(&h_out[(size_t)n * 256 + colb]) = pk;
        }
    }
}

// ------------------------------------------------- MFMA tail: fc + dlog + losses
// Per wave: 16 nodes. T1 = h1_tile @ Wt1^T (cols 0-9 fc, 10/11 dlog-h1),
// T2 = h0_tile @ Wt2^T (cols 0/1 dlog-h0). Block-partial losses, NO global atomics.
__global__ __launch_bounds__(256) void k_tail_mfma(
        const ushort* __restrict__ h0, const ushort* __restrict__ h1,
        const ushort* __restrict__ Wt1, const ushort* __restrict__ Wt2,
        const float* __restrict__ bfc, const float* __restrict__ bd,
        const int* __restrict__ labels, int g,
        float* __restrict__ pcls, float* __restrict__ pdom) {
    __shared__ float sT1[4][16][17];
    __shared__ float sT2[4][16][17];
    __shared__ float sc[4], sd[4];
    const int tid = threadIdx.x;
    const int wid = tid >> 6, lane = tid & 63;
    const int l15 = lane & 15, lg = lane >> 4;
    const int base = blockIdx.x * 64 + wid * 16;

    int arow = base + l15; if (arow >= NN) arow = NN - 1;
    const ushort* a1 = h1 + (size_t)arow * 256 + lg * 8;
    const ushort* a0 = h0 + (size_t)arow * 256 + lg * 8;
    const ushort* b1 = Wt1 + (size_t)l15 * 256 + lg * 8;
    const ushort* b2 = Wt2 + (size_t)l15 * 256 + lg * 8;
    f32x4 acc1 = {0.f, 0.f, 0.f, 0.f};
    f32x4 acc2 = {0.f, 0.f, 0.f, 0.f};
    #pragma unroll
    for (int kk = 0; kk < 8; ++kk) {
        bfrag af1 = *reinterpret_cast<const bfrag*>(a1 + kk * 32);
        bfrag bg1 = *reinterpret_cast<const bfrag*>(b1 + kk * 32);
        acc1 = __builtin_amdgcn_mfma_f32_16x16x32_bf16(af1, bg1, acc1, 0, 0, 0);
        bfrag af0 = *reinterpret_cast<const bfrag*>(a0 + kk * 32);
        bfrag bg2 = *reinterpret_cast<const bfrag*>(b2 + kk * 32);
        acc2 = __builtin_amdgcn_mfma_f32_16x16x32_bf16(af0, bg2, acc2, 0, 0, 0);
    }
    #pragma unroll
    for (int j = 0; j < 4; ++j) {
        sT1[wid][lg * 4 + j][l15] = acc1[j];
        sT2[wid][lg * 4 + j][l15] = acc2[j];
    }
    __syncthreads();

    float cls = 0.f, dom = 0.f;
    int n = base + lane;
    if (lane < 16 && n < NN) {
        float lgt[10];
        #pragma unroll
        for (int c = 0; c < 10; ++c) lgt[c] = sT1[wid][lane][c] + bfc[c];
        float dl0 = bd[0] + sT2[wid][lane][0] + sT1[wid][lane][10];
        float dl1 = bd[1] + sT2[wid][lane][1] + sT1[wid][lane][11];
        if (g == 0) {
            float m = lgt[0];
            #pragma unroll
            for (int c = 1; c < 10; ++c) m = fmaxf(m, lgt[c]);
            float s = 0.f;
            #pragma unroll
            for (int c = 0; c < 10; ++c) s += expf(lgt[c] - m);
            int lab = labels[n];
            float tgt = lgt[0];
            #pragma unroll
            for (int c = 1; c < 10; ++c) tgt = (c == lab) ? lgt[c] : tgt;
            cls = -(tgt - (m + logf(s)));
        }
        float m2 = fmaxf(dl0, dl1);
        float lse2 = m2 + logf(expf(dl0 - m2) + expf(dl1 - m2));
        dom = -((g ? dl1 : dl0) - lse2);
    }
    // reduce lanes 0-15 -> lane 0
    #pragma unroll
    for (int o = 1; o < 16; o <<= 1) {
        cls += __shfl_xor(cls, o, 64);
        dom += __shfl_xor(dom, o, 64);
    }
    if (lane == 0) { sc[wid] = cls; sd[wid] = dom; }
    __syncthreads();
    if (tid == 0) {
        float c = sc[0] + sc[1] + sc[2] + sc[3];
        float d = sd[0] + sd[1] + sd[2] + sd[3];
        if (g == 0) pcls[blockIdx.x] = c;
        pdom[g * NTB + blockIdx.x] = d;
    }
}

__global__ void k_finalize(const float* __restrict__ pcls, const float* __restrict__ pdom,
                           float* __restrict__ out) {
    __shared__ float sc[4], sd[4];
    int tid = threadIdx.x, lane = tid & 63, wid = tid >> 6;
    float c = 0.f, d = 0.f;
    for (int i = tid; i < NTB; i += 256) c += pcls[i];
    for (int i = tid; i < 2 * NTB; i += 256) d += pdom[i];
    #pragma unroll
    for (int o = 32; o; o >>= 1) {
        c += __shfl_xor(c, o, 64);
        d += __shfl_xor(d, o, 64);
    }
    if (lane == 0) { sc[wid] = c; sd[wid] = d; }
    __syncthreads();
    if (tid == 0) {
        float ct = sc[0] + sc[1] + sc[2] + sc[3];
        float dt = sd[0] + sd[1] + sd[2] + sd[3];
        out[0] = ct / (float)NN + 0.01f * (dt / (float)(2 * NN));
    }
}

// ---------------------------------------------------------------- launch
extern "C" void kernel_launch(void* const* d_in, const int* in_sizes, int n_in,
                              void* d_out, int out_size, void* d_ws, size_t ws_size,
                              hipStream_t stream) {
    const float* features_s = (const float*)d_in[0];
    const int*   labels_s   = (const int*)d_in[1];
    const float* features_t = (const float*)d_in[2];
    const int*   src_s      = (const int*)d_in[3];
    const int*   dst_s      = (const int*)d_in[4];
    const int*   src_t      = (const int*)d_in[5];
    const int*   dst_t      = (const int*)d_in[6];
    const float* W0         = (const float*)d_in[7];
    const float* b0         = (const float*)d_in[8];
    const float* W1         = (const float*)d_in[9];
    const float* b1         = (const float*)d_in[10];
    const float* Wfc        = (const float*)d_in[11];
    const float* bfc        = (const float*)d_in[12];
    const float* Wd         = (const float*)d_in[13];
    const float* bd         = (const float*)d_in[14];
    float* out = (float*)d_out;

    auto align256 = [](size_t x) { return (x + 255) & ~(size_t)255; };
    char* w = (char*)d_ws;
    ushort* h0     = (ushort*)w; w += align256((size_t)NN * HH * 2);   // 25.6 MB
    ushort* h1     = (ushort*)w; w += align256((size_t)NN * HH * 2);   // 25.6 MB
    ushort* ybuf   = (ushort*)w; w += align256((size_t)NN * HH * 2);   // 25.6 MB
    ushort* W0t    = (ushort*)w; w += align256((size_t)INF * HH * 2);
    ushort* W1t    = (ushort*)w; w += align256((size_t)HH * HH * 2);
    ushort* Wt1    = (ushort*)w; w += align256((size_t)16 * HH * 2);
    ushort* Wt2    = (ushort*)w; w += align256((size_t)16 * HH * 2);
    float* norm_src= (float*)w;  w += align256((size_t)NN * 4);
    float* norm_dst= (float*)w;  w += align256((size_t)NN * 4);
    int*   cnt     = (int*)w;    w += align256((size_t)2 * NN * 4);
    int*   csr_off = (int*)w;    w += align256((size_t)(NN + 1) * 4);
    int*   csr_cur = (int*)w;    w += align256((size_t)NN * 4);
    int*   csr_src = (int*)w;    w += align256((size_t)EE * 4);
    int*   btot    = (int*)w;    w += align256((size_t)NB * 4);
    int*   bbase   = (int*)w;    w += align256((size_t)NB * 4);
    float* pcls    = (float*)w;  w += align256((size_t)NTB * 4);
    float* pdom    = (float*)w;  w += align256((size_t)2 * NTB * 4);
    int* cnt_out = cnt;
    int* cnt_in  = cnt + NN;

    const int TB = 256;
    k_cast_wt<INF><<<(INF * HH + TB - 1) / TB, TB, 0, stream>>>(W0, W0t);
    k_cast_wt<HH><<<(HH * HH + TB - 1) / TB, TB, 0, stream>>>(W1, W1t);
    k_cast_wtail<<<(16 * HH + TB - 1) / TB, TB, 0, stream>>>(Wfc, Wd, Wt1);
    k_cast_wtail2<<<(16 * HH + TB - 1) / TB, TB, 0, stream>>>(Wd, Wt2);

    for (int g = 0; g < 2; ++g) {
        const float* feats = g ? features_t : features_s;
        const int* src = g ? src_t : src_s;
        const int* dst = g ? dst_t : dst_s;

        hipMemsetAsync(cnt, 0, (size_t)2 * NN * 4, stream);
        k_degrees<<<(EE + TB - 1) / TB, TB, 0, stream>>>(src, dst, cnt_out, cnt_in);
        k_scan_blk<<<NB, TB, 0, stream>>>(cnt_in, csr_off, btot);
        k_scan_tops<<<1, TB, 0, stream>>>(btot, bbase, csr_off);
        k_scan_fin<<<NB, TB, 0, stream>>>(csr_off, bbase, csr_cur, cnt_out, cnt_in,
                                          norm_src, norm_dst);
        k_fill<<<(EE + TB - 1) / TB, TB, 0, stream>>>(src, dst, csr_cur, csr_src);

        // layer 0: ybuf = (feats @ W0)*ns ; h0 = relu(agg*nd + b0)
        k_gemm<INF, true><<<dim3((NN + 127) / 128, 2), TB, 0, stream>>>(feats, W0t, norm_src, ybuf);
        k_spmm2<<<GPB * 8, TB, 0, stream>>>(ybuf, csr_off, csr_src, norm_dst, b0, h0);

        // layer 1: ybuf = (h0 @ W1)*ns ; h1 = relu(agg*nd + b1)
        k_gemm<HH, false><<<dim3((NN + 127) / 128, 2), TB, 0, stream>>>(h0, W1t, norm_src, ybuf);
        k_spmm2<<<GPB * 8, TB, 0, stream>>>(ybuf, csr_off, csr_src, norm_dst, b1, h1);

        // fc head + dlog (both layers) + losses, block-partial outputs
        k_tail_mfma<<<NTB, TB, 0, stream>>>(h0, h1, Wt1, Wt2, bfc, bd, labels_s, g, pcls, pdom);
    }
    k_finalize<<<1, TB, 0, stream>>>(pcls, pdom, out);
}